// Round 1
// baseline (1596.646 us; speedup 1.0000x reference)
//
#include <hip/hip_runtime.h>
#include <cstdint>

// Problem constants (fixed by the reference's setup_inputs).
namespace {
constexpr int kC   = 80;              // channels
constexpr int kC4  = 20;              // float4 per row
constexpr int kW   = 360;
constexpr int kH   = 360;
constexpr int kD   = 1;
constexpr int kB   = 4;
constexpr int kR0  = kW * kD * kB;    // 1440  (rank stride for c0)
constexpr int kR1  = kD * kB;         // 4     (rank stride for c1)
constexpr int kR2  = kB;              // 4     (rank stride for c2; c2==0 since D=1)
constexpr int kNR  = kW * kH * kD * kB;     // 518400 rank bins
constexpr int kOutRows = kB * kD * kH * kW; // 518400 output rows
}

__device__ __forceinline__ int rank_of(const int4 co) {
    return co.x * kR0 + co.y * kR1 + co.z * kR2 + co.w;
}

// geom = c0 + c1*W + c2*H + c3, with c2==0 (D=1).
__device__ __forceinline__ int geom_of(int r) {
    int c0  = r / kR0;
    int rem = r - c0 * kR0;
    int c1  = rem >> 2;   // rem / 4
    int c3  = rem & 3;    // rem % 4
    return c0 + c1 * kW + c3;
}

// Pass A: per-rank count, min original index, global max rank.
__global__ void k_hist(const int4* __restrict__ coords, int n,
                       int* __restrict__ cnt, int* __restrict__ minidx,
                       int* __restrict__ rmax) {
    int i = blockIdx.x * blockDim.x + threadIdx.x;
    int r = -1;
    if (i < n) {
        int4 co = coords[i];
        r = rank_of(co);
        atomicAdd(&cnt[r], 1);
        atomicMin(&minidx[r], i);
    }
    // wave-reduce the max rank to avoid 800K same-address atomics
    int wmax = r;
    #pragma unroll
    for (int off = 32; off > 0; off >>= 1)
        wmax = max(wmax, __shfl_xor(wmax, off));
    if ((threadIdx.x & 63) == 0 && wmax >= 0) atomicMax(rmax, wmax);
}

// Pass A2: previous non-empty rank for each non-empty rank (-1 if none).
__global__ void k_prev(const int* __restrict__ cnt, int* __restrict__ prevrank) {
    int r = blockIdx.x * blockDim.x + threadIdx.x;
    if (r >= kNR) return;
    if (cnt[r] == 0) return;
    int p = r - 1;
    while (p >= 0 && cnt[p] == 0) --p;   // avg gap ~1.3 bins for random data
    prevrank[r] = p;
}

// Pass B (big-ws path): scatter feats into rank-indexed sum buffer.
// The group's FIRST point (minidx) redirects to prevrank -> implements
// (sum_r - first_r + first_next) without any sorting. Also reduces total[80].
__global__ __launch_bounds__(320) void k_scatter(
    const float4* __restrict__ feats4, const int4* __restrict__ coords, int n,
    const int* __restrict__ minidx, const int* __restrict__ prevrank,
    float* __restrict__ sumbuf, float* __restrict__ total)
{
    const int tid = threadIdx.x;
    const int stride = gridDim.x * 320;        // multiple of 20 -> c4 fixed/thread
    const int tot4 = n * kC4;
    float4 ls = make_float4(0.f, 0.f, 0.f, 0.f);
    for (int e = blockIdx.x * 320 + tid; e < tot4; e += stride) {
        float4 f = feats4[e];
        int p  = e / kC4;
        int c4 = e - p * kC4;
        int4 co = coords[p];
        int r = rank_of(co);
        int tgt = (minidx[r] == p) ? prevrank[r] : r;
        if (tgt >= 0) {
            float* dst = sumbuf + (size_t)tgt * kC + (c4 << 2);
            atomicAdd(dst + 0, f.x);
            atomicAdd(dst + 1, f.y);
            atomicAdd(dst + 2, f.z);
            atomicAdd(dst + 3, f.w);
        }
        ls.x += f.x; ls.y += f.y; ls.z += f.z; ls.w += f.w;
    }
    __shared__ float tot[kC];
    if (tid < kC) tot[tid] = 0.f;
    __syncthreads();
    const int c4f = tid % kC4;
    atomicAdd(&tot[(c4f << 2) + 0], ls.x);
    atomicAdd(&tot[(c4f << 2) + 1], ls.y);
    atomicAdd(&tot[(c4f << 2) + 2], ls.z);
    atomicAdd(&tot[(c4f << 2) + 3], ls.w);
    __syncthreads();
    if (tid < kC) atomicAdd(&total[tid], tot[tid]);
}

// Pass C (big-ws path): pure gather into out. For each output row g,
// enumerate the <=8 ranks with geom(r)==g in closed form. No atomics.
__global__ void k_out(const int* __restrict__ cnt,
                      const float4* __restrict__ sumbuf4,
                      const float4* __restrict__ total4,
                      const int* __restrict__ rmax,
                      float4* __restrict__ out4)
{
    int idx = blockIdx.x * blockDim.x + threadIdx.x;
    if (idx >= kOutRows * kC4) return;
    int g  = idx / kC4;
    int c4 = idx - g * kC4;
    const int rmaxv = *rmax;
    float4 acc = make_float4(0.f, 0.f, 0.f, 0.f);
    int q   = g / kW;
    int rem = g - q * kW;
    #pragma unroll
    for (int pass = 0; pass < 2; ++pass) {
        int c1 = q - pass;
        int s  = rem + pass * kW;                 // s = c0 + c3
        if (c1 < 0 || c1 >= kH || s > (kW - 1) + (kB - 1)) continue;
        int c3lo = s - (kW - 1); if (c3lo < 0) c3lo = 0;
        int c3hi = (s < kB - 1) ? s : (kB - 1);
        for (int c3 = c3lo; c3 <= c3hi; ++c3) {
            int c0 = s - c3;
            int r  = c0 * kR0 + c1 * kR1 + c3;
            int cn = cnt[r];
            if (cn > 0) {
                float4 v = (r == rmaxv) ? total4[c4]
                                        : sumbuf4[(size_t)r * kC4 + c4];
                float fc = (float)cn;
                acc.x += fc * v.x; acc.y += fc * v.y;
                acc.z += fc * v.z; acc.w += fc * v.w;
            }
        }
    }
    out4[idx] = acc;
}

// Small-ws fallback: scatter (cnt-scaled) straight into zeroed d_out.
__global__ __launch_bounds__(320) void k_scatter_direct(
    const float4* __restrict__ feats4, const int4* __restrict__ coords, int n,
    const int* __restrict__ cnt, const int* __restrict__ minidx,
    const int* __restrict__ prevrank, const int* __restrict__ rmax,
    float* __restrict__ out, float* __restrict__ total)
{
    const int tid = threadIdx.x;
    const int stride = gridDim.x * 320;
    const int tot4 = n * kC4;
    const int rmaxv = *rmax;
    float4 ls = make_float4(0.f, 0.f, 0.f, 0.f);
    for (int e = blockIdx.x * 320 + tid; e < tot4; e += stride) {
        float4 f = feats4[e];
        int p  = e / kC4;
        int c4 = e - p * kC4;
        int4 co = coords[p];
        int r = rank_of(co);
        int tgt = (minidx[r] == p) ? prevrank[r] : r;
        if (tgt >= 0 && tgt != rmaxv) {
            float fc = (float)cnt[tgt];
            float* dst = out + (size_t)geom_of(tgt) * kC + (c4 << 2);
            atomicAdd(dst + 0, fc * f.x);
            atomicAdd(dst + 1, fc * f.y);
            atomicAdd(dst + 2, fc * f.z);
            atomicAdd(dst + 3, fc * f.w);
        }
        ls.x += f.x; ls.y += f.y; ls.z += f.z; ls.w += f.w;
    }
    __shared__ float tot[kC];
    if (tid < kC) tot[tid] = 0.f;
    __syncthreads();
    const int c4f = tid % kC4;
    atomicAdd(&tot[(c4f << 2) + 0], ls.x);
    atomicAdd(&tot[(c4f << 2) + 1], ls.y);
    atomicAdd(&tot[(c4f << 2) + 2], ls.z);
    atomicAdd(&tot[(c4f << 2) + 3], ls.w);
    __syncthreads();
    if (tid < kC) atomicAdd(&total[tid], tot[tid]);
}

__global__ void k_lastfix(const int* __restrict__ cnt, const int* __restrict__ rmax,
                          const float* __restrict__ total, float* __restrict__ out) {
    int t = threadIdx.x;
    if (t >= kC) return;
    int r = *rmax;
    atomicAdd(&out[(size_t)geom_of(r) * kC + t], (float)cnt[r] * total[t]);
}

extern "C" void kernel_launch(void* const* d_in, const int* in_sizes, int n_in,
                              void* d_out, int out_size, void* d_ws, size_t ws_size,
                              hipStream_t stream) {
    (void)n_in;
    const float* feats  = (const float*)d_in[0];
    const int*   coords = (const int*)d_in[1];
    const int n = in_sizes[1] / 4;   // 800000

    char* ws = (char*)d_ws;
    size_t off = 0;
    int*   cnt      = (int*)(ws + off);  off += (size_t)kNR * 4;
    int*   minidx   = (int*)(ws + off);  off += (size_t)kNR * 4;
    int*   prevrank = (int*)(ws + off);  off += (size_t)kNR * 4;
    int*   rmax     = (int*)(ws + off);  off += 16;
    float* total    = (float*)(ws + off); off += 384;         // 80*4 padded
    float* sumbuf   = (float*)(ws + off);
    const size_t need_big = off + (size_t)kNR * kC * 4;       // ~172 MB
    const bool big = ws_size >= need_big;

    hipMemsetAsync(cnt,    0,    (size_t)kNR * 4, stream);
    hipMemsetAsync(minidx, 0x7F, (size_t)kNR * 4, stream);    // 0x7F7F7F7F > n
    hipMemsetAsync(rmax,   0,    16, stream);
    hipMemsetAsync(total,  0,    384, stream);

    k_hist<<<(n + 255) / 256, 256, 0, stream>>>((const int4*)coords, n, cnt, minidx, rmax);
    k_prev<<<(kNR + 255) / 256, 256, 0, stream>>>(cnt, prevrank);

    if (big) {
        hipMemsetAsync(sumbuf, 0, (size_t)kNR * kC * 4, stream);
        k_scatter<<<1024, 320, 0, stream>>>((const float4*)feats, (const int4*)coords, n,
                                            minidx, prevrank, sumbuf, total);
        const int tot_el = kOutRows * kC4;   // 10,368,000
        k_out<<<(tot_el + 255) / 256, 256, 0, stream>>>(cnt, (const float4*)sumbuf,
                                                        (const float4*)total, rmax,
                                                        (float4*)d_out);
    } else {
        hipMemsetAsync(d_out, 0, (size_t)out_size * 4, stream);
        k_scatter_direct<<<1024, 320, 0, stream>>>((const float4*)feats, (const int4*)coords, n,
                                                   cnt, minidx, prevrank, rmax,
                                                   (float*)d_out, total);
        k_lastfix<<<1, 128, 0, stream>>>(cnt, rmax, total, (float*)d_out);
    }
}

// Round 2
// 655.044 us; speedup vs baseline: 2.4375x; 2.4375x over previous
//
#include <hip/hip_runtime.h>
#include <cstdint>

// Problem constants (fixed by the reference's setup_inputs).
namespace {
constexpr int kC   = 80;              // channels
constexpr int kC4  = 20;              // float4 per row
constexpr int kW   = 360;
constexpr int kH   = 360;
constexpr int kB   = 4;
constexpr int kR0  = kW * 1 * kB;     // 1440  (rank stride for c0; D=1)
constexpr int kR1  = 1 * kB;          // 4     (rank stride for c1)
constexpr int kR2  = kB;              // 4     (rank stride for c2; c2==0)
constexpr int kNR  = kW * kH * kB;    // 518400 rank bins
constexpr int kOutRows = kB * kH * kW; // 518400 output rows
}

__device__ __forceinline__ int rank_of(const int4 co) {
    return co.x * kR0 + co.y * kR1 + co.z * kR2 + co.w;
}

__device__ __forceinline__ float4 f4add(float4 a, float4 b) {
    return make_float4(a.x + b.x, a.y + b.y, a.z + b.z, a.w + b.w);
}

// Pass A: per-rank count, min original index, global max rank, total[80].
// Grid-stride over N*kC4 float4 elements; stride is a multiple of kC4 so each
// thread's c4 phase is fixed (clean LDS total reduction).
__global__ __launch_bounds__(320) void k_hist(
    const float4* __restrict__ feats4, const int4* __restrict__ coords, int n,
    int* __restrict__ cnt, int* __restrict__ minidx, int* __restrict__ rmax,
    float* __restrict__ total)
{
    const int tid = threadIdx.x;
    const int stride = gridDim.x * 320;      // multiple of 20
    const int tot4 = n * kC4;
    float4 ls = make_float4(0.f, 0.f, 0.f, 0.f);
    int wmaxr = -1;
    for (int e = blockIdx.x * 320 + tid; e < tot4; e += stride) {
        float4 f = feats4[e];
        ls = f4add(ls, f);
        int p  = e / kC4;
        int c4 = e - p * kC4;
        if (c4 == 0) {
            int r = rank_of(coords[p]);
            atomicAdd(&cnt[r], 1);
            atomicMin(&minidx[r], p);
            wmaxr = max(wmaxr, r);
        }
    }
    #pragma unroll
    for (int off = 32; off > 0; off >>= 1)
        wmaxr = max(wmaxr, __shfl_xor(wmaxr, off));
    if ((tid & 63) == 0 && wmaxr >= 0) atomicMax(rmax, wmaxr);

    __shared__ float tot[kC];
    if (tid < kC) tot[tid] = 0.f;
    __syncthreads();
    const int c4f = tid % kC4;
    atomicAdd(&tot[(c4f << 2) + 0], ls.x);
    atomicAdd(&tot[(c4f << 2) + 1], ls.y);
    atomicAdd(&tot[(c4f << 2) + 2], ls.z);
    atomicAdd(&tot[(c4f << 2) + 3], ls.w);
    __syncthreads();
    if (tid < kC) atomicAdd(&total[tid], tot[tid]);
}

// Pass B: per-rank base offsets. Block-local exclusive scan of cnt, one
// atomicAdd per block for the base. Offsets form a valid partition of [0,N)
// (ordering across blocks irrelevant for correctness).
__global__ void k_offset(const int* __restrict__ cnt, int* __restrict__ offset,
                         int* __restrict__ counter) {
    const int b = blockIdx.x * 256 + threadIdx.x;
    const int lane = threadIdx.x & 63, wid = threadIdx.x >> 6;
    int v = (b < kNR) ? cnt[b] : 0;
    int incl = v;
    #pragma unroll
    for (int d = 1; d < 64; d <<= 1) {
        int t = __shfl_up(incl, d);
        if (lane >= d) incl += t;
    }
    __shared__ int wsum[4];
    __shared__ int base;
    if (lane == 63) wsum[wid] = incl;
    __syncthreads();
    if (threadIdx.x == 0) {
        int s0 = 0;
        int tmp[4];
        #pragma unroll
        for (int i = 0; i < 4; ++i) { tmp[i] = s0; s0 += wsum[i]; }
        #pragma unroll
        for (int i = 0; i < 4; ++i) wsum[i] = tmp[i];
        base = atomicAdd(counter, s0);
    }
    __syncthreads();
    if (b < kNR) offset[b] = base + wsum[wid] + (incl - v);
}

// Pass C: fill CSR point lists.
__global__ void k_fill(const int4* __restrict__ coords, int n,
                       const int* __restrict__ offset, int* __restrict__ fill,
                       int* __restrict__ idxbuf) {
    int p = blockIdx.x * 256 + threadIdx.x;
    if (p >= n) return;
    int r = rank_of(coords[p]);
    int slot = atomicAdd(&fill[r], 1);
    idxbuf[offset[r] + slot] = p;
}

// Pass D: for each nonempty rank r, give its previous nonempty rank p the
// "extra" point minidx[r] (the redirected first-of-next-group). Unique writer.
__global__ void k_extra(const int* __restrict__ cnt, const int* __restrict__ minidx,
                        int* __restrict__ extraidx) {
    int r = blockIdx.x * 256 + threadIdx.x;
    if (r >= kNR || cnt[r] == 0) return;
    int p = r - 1;
    while (p >= 0 && cnt[p] == 0) --p;   // avg gap ~1.3 bins
    if (p >= 0) extraidx[p] = minidx[r];
}

// Pass E: pure gather. For each output element (g, c4), enumerate the <=8
// ranks with geom(r)==g, sum that rank's effective point set directly from
// feats. No atomics, no memset of d_out (zero rows written naturally).
__global__ void k_out(const int* __restrict__ cnt, const int* __restrict__ offset,
                      const int* __restrict__ minidx, const int* __restrict__ extraidx,
                      const int* __restrict__ idxbuf,
                      const float4* __restrict__ feats4,
                      const float4* __restrict__ total4,
                      const int* __restrict__ rmax,
                      float4* __restrict__ out4)
{
    int idx = blockIdx.x * 256 + threadIdx.x;
    if (idx >= kOutRows * kC4) return;
    int g  = idx / kC4;
    int c4 = idx - g * kC4;
    const int rmaxv = *rmax;
    float4 acc = make_float4(0.f, 0.f, 0.f, 0.f);
    int q   = g / kW;
    int rem = g - q * kW;
    #pragma unroll
    for (int pass = 0; pass < 2; ++pass) {
        int c1 = q - pass;
        int s  = rem + pass * kW;                 // s = c0 + c3
        if (c1 < 0 || c1 >= kH || s > (kW - 1) + (kB - 1)) continue;
        int c3lo = s - (kW - 1); if (c3lo < 0) c3lo = 0;
        int c3hi = (s < kB - 1) ? s : (kB - 1);
        for (int c3 = c3lo; c3 <= c3hi; ++c3) {
            int c0 = s - c3;
            int r  = c0 * kR0 + c1 * kR1 + c3;
            int cn = cnt[r];
            if (cn <= 0) continue;
            float fc = (float)cn;
            if (r == rmaxv) {
                float4 v = total4[c4];
                acc.x += fc * v.x; acc.y += fc * v.y;
                acc.z += fc * v.z; acc.w += fc * v.w;
            } else {
                int off = offset[r];
                int mi  = minidx[r];
                int ex  = extraidx[r];           // exists: r nonempty, r != last
                float4 sum = feats4[(size_t)ex * kC4 + c4];
                for (int j = 0; j < cn; ++j) {
                    int p = idxbuf[off + j];
                    if (p != mi) {
                        float4 f = feats4[(size_t)p * kC4 + c4];
                        sum = f4add(sum, f);
                    }
                }
                acc.x += fc * sum.x; acc.y += fc * sum.y;
                acc.z += fc * sum.z; acc.w += fc * sum.w;
            }
        }
    }
    out4[idx] = acc;
}

extern "C" void kernel_launch(void* const* d_in, const int* in_sizes, int n_in,
                              void* d_out, int out_size, void* d_ws, size_t ws_size,
                              hipStream_t stream) {
    (void)n_in; (void)out_size; (void)ws_size;
    const float* feats  = (const float*)d_in[0];
    const int*   coords = (const int*)d_in[1];
    const int n = in_sizes[1] / 4;   // 800000

    char* ws = (char*)d_ws;
    size_t off = 0;
    int*   cnt      = (int*)(ws + off);   off += (size_t)kNR * 4;
    int*   minidx   = (int*)(ws + off);   off += (size_t)kNR * 4;
    int*   offsetb  = (int*)(ws + off);   off += (size_t)kNR * 4;
    int*   fill     = (int*)(ws + off);   off += (size_t)kNR * 4;
    int*   extraidx = (int*)(ws + off);   off += (size_t)kNR * 4;
    int*   idxbuf   = (int*)(ws + off);   off += (size_t)n * 4;
    int*   rmax     = (int*)(ws + off);   off += 16;
    int*   counter  = (int*)(ws + off);   off += 16;
    float* total    = (float*)(ws + off); off += 384;   // 80*4 padded

    hipMemsetAsync(cnt,      0,    (size_t)kNR * 4, stream);
    hipMemsetAsync(minidx,   0x7F, (size_t)kNR * 4, stream);  // > n
    hipMemsetAsync(fill,     0,    (size_t)kNR * 4, stream);
    hipMemsetAsync(extraidx, 0xFF, (size_t)kNR * 4, stream);  // -1
    hipMemsetAsync(rmax,     0,    16, stream);
    hipMemsetAsync(counter,  0,    16, stream);
    hipMemsetAsync(total,    0,    384, stream);

    k_hist<<<1024, 320, 0, stream>>>((const float4*)feats, (const int4*)coords, n,
                                     cnt, minidx, rmax, total);
    k_offset<<<(kNR + 255) / 256, 256, 0, stream>>>(cnt, offsetb, counter);
    k_fill<<<(n + 255) / 256, 256, 0, stream>>>((const int4*)coords, n,
                                                offsetb, fill, idxbuf);
    k_extra<<<(kNR + 255) / 256, 256, 0, stream>>>(cnt, minidx, extraidx);

    const int tot_el = kOutRows * kC4;   // 10,368,000
    k_out<<<(tot_el + 255) / 256, 256, 0, stream>>>(cnt, offsetb, minidx, extraidx,
                                                    idxbuf, (const float4*)feats,
                                                    (const float4*)total, rmax,
                                                    (float4*)d_out);
}